// Round 15
// baseline (39.832 us; speedup 1.0000x reference)
//
#include <hip/hip_runtime.h>

#define SN 128
#define SPK 512

constexpr float GMIN  = 0.1f;
constexpr float PFRAC = 0.3f;
constexpr float GMAX  = 1.0f;

// Single-kernel fill + scatter.
// Lazy decay: v(n) = C(n)*a + GMIN, C(n) = exp((ts0-ts[n])/TAU) <= 1.
// Untouched cell at snapshot r: u_r = GMIN*(1-C_r)  (identical everywhere).
// Touch at step n: a' = (1-PFRAC)*a + PFRAC*(GMAX-GMIN)/C(n); amplitude is
// NON-DECREASING over the touch prefix, so per-touch own-prefix candidates
// combined with atomicMax reproduce the exact final value (verified R11,
// absmax 0.0). All candidates >= u_r >= 0 -> int-compare atomicMax is valid.
// Fill (plain stores) precedes scatter (atomicMax) with a block barrier;
// blocks own disjoint (sample, slot-pair) output planes -> no cross-block
// ordering needed; fill-then-max is idempotent across graph replays.
//
// Block = (s, rblk): slots {2rblk, 2rblk+1} of sample s. 512 threads = one
// thread per event step n.

__global__ __launch_bounds__(512, 2) void fuse_kernel(
    const int*   __restrict__ event,   // (SN, SPK, 3) int32: x, y, pol
    const float* __restrict__ ts,      // (SN, SPK) f32, ascending
    const int*   __restrict__ tt,      // (SN, SPK) int32 in [0,8)
    const int*   __restrict__ length,  // (SN,) int32
    float*       __restrict__ out)     // (SN, 8, 2, 64, 64) f32
{
    __shared__ unsigned skey[SPK];     // key or ~0u if not a touch
    __shared__ float    sCr [SPK];     // PFRAC*(GMAX-GMIN)/C(n)
    __shared__ float    stsn[SPK];
    __shared__ int      snl [8];
    __shared__ float    sC  [8];       // C_r
    __shared__ float    sU  [8];       // u_r

    const int blk  = blockIdx.x;
    const int s    = blk >> 2;
    const int rblk = blk & 3;
    const int t    = threadIdx.x;      // event index n = t

    const int   len = length[s];
    const float ts0 = ts[s * SPK];

    // issue my event loads early
    const int* ev = event + (size_t)(s * SPK + t) * 3;
    const int   ex  = ev[0], ey = ev[1], ep = ev[2];
    const float tsn = ts[s * SPK + t];
    const int   tv  = tt[s * SPK + t];

    if (t < 8) snl[t] = -1;
    __syncthreads();

    // ---- stage events + snlast ----
    const bool     gate = (t < len);                 // t==0 always (len>=1)
    const unsigned key  = (unsigned)((ep << 14) | (ex << 7) | ey);
    const float    d    = (ts0 - tsn) * 0.01f;       // TAU = 100
    skey[t] = gate ? key : 0xFFFFFFFFu;
    sCr [t] = (PFRAC * (GMAX - GMIN)) * __expf(-d);  // 0.27 / C(n)
    stsn[t] = tsn;
    if (t >= 1) atomicMax(&snl[tv], t);
    __syncthreads();

    // ---- per-slot table (threads 0..7) ----
    if (t < 8) {
        int nr = snl[t];
        if (t == 0 && nr < 0) nr = 0;                // slot0 falls back to init state
        float C = 0.0f, u = 0.0f;
        if (nr >= 0) {
            C = __expf((ts0 - stsn[nr]) * 0.01f);    // C_r <= 1
            u = GMIN - C * GMIN;                     // untouched value
        }
        snl[t] = nr;
        sC [t] = C;
        sU [t] = u;
    }
    __syncthreads();

    // ---- fill: 64 KB contiguous (2 slots x 2 pol x 64 x 64) ----
    {
        float4* o4 = reinterpret_cast<float4*>(out) + (size_t)(s * 8 + rblk * 2) * 2048;
        const float u0 = sU[rblk * 2];
        const float u1 = sU[rblk * 2 + 1];
#pragma unroll
        for (int k = 0; k < 8; ++k) {
            int f = k * 512 + t;                     // 0..4095 float4
            float u = (f < 2048) ? u0 : u1;
            o4[f] = make_float4(u, u, u, u);
        }
    }

    // ---- own-prefix amplitude (broadcast LDS scan; overlaps store drain) ----
    float a = -GMIN;
    if (gate) {
        for (int j = 0; j < t; ++j) {
            if (skey[j] == key)
                a = (j == 0) ? (PFRAC * (GMAX - GMIN) - GMIN)   // init SETs 0.27
                             : fmaf(1.0f - PFRAC, a, sCr[j]);
        }
        a = (t == 0) ? (PFRAC * (GMAX - GMIN) - GMIN)
                     : fmaf(1.0f - PFRAC, a, sCr[t]);
    }

    __syncthreads();   // fill stores drained before any atomicMax

    // ---- scatter to this block's two slots ----
    if (gate) {
        const int Xo = ex >> 1, Yo = ey >> 1;
        int* oi = reinterpret_cast<int*>(out);
#pragma unroll
        for (int rl = 0; rl < 2; ++rl) {
            int r  = rblk * 2 + rl;
            int nr = snl[r];
            if (t <= nr) {
                float val = fmaf(sC[r], a, GMIN);    // >= u_r >= 0
                int   idx = (((s * 8 + r) * 2 + ep) * 64 + Xo) * 64 + Yo;
                atomicMax(oi + idx, __float_as_int(val));
            }
        }
    }
}

extern "C" void kernel_launch(void* const* d_in, const int* in_sizes, int n_in,
                              void* d_out, int out_size, void* d_ws, size_t ws_size,
                              hipStream_t stream) {
    const int*   event  = (const int*)  d_in[0];
    const float* ts     = (const float*)d_in[1];
    const int*   tt     = (const int*)  d_in[2];
    const int*   length = (const int*)  d_in[3];
    float*       out    = (float*)d_out;

    // 128 samples x 4 slot-pairs = 512 blocks x 512 threads
    fuse_kernel<<<dim3(SN * 4), dim3(512), 0, stream>>>(event, ts, tt, length, out);
}

// Round 17
// 25.058 us; speedup vs baseline: 1.5896x; 1.5896x over previous
//
#include <hip/hip_runtime.h>

#define SN 128
#define SPK 512
#define HB 4096     // hash buckets

constexpr float GMIN  = 0.1f;
constexpr float PFRAC = 0.3f;
constexpr float GMAX  = 1.0f;

// Single-kernel fill + scatter, with ambiguous-only duplicate resolution.
// Lazy decay: v(n) = C(n)*a + GMIN, C(n) = exp((ts0-ts[n])/TAU) <= 1.
// Untouched cell at snapshot r: u_r = GMIN*(1-C_r) (identical everywhere).
// Touch at n: a' = (1-PFRAC)*a + PFRAC*(GMAX-GMIN)/C(n); amplitude is
// non-decreasing over the touch prefix -> per-touch own-prefix candidates +
// atomicMax reproduce the exact final value (verified absmax 0.0, R11/R15).
// Duplicate (same-cell) predecessors are found by: hash-count buckets; only
// events in buckets with count>=2 (~60/block, incl. collisions; no false
// negatives) are ballot-compacted into a time-ordered list, and only they
// scan it (~60 iters) -- replaces R15's O(512) serial LDS scan per thread.
//
// Block = (s, rblk): slots {2rblk, 2rblk+1} of sample s; 512 threads = one
// thread per event step. Blocks own disjoint output planes.

__global__ __launch_bounds__(512, 2) void fuse_kernel(
    const int*   __restrict__ event,   // (SN, SPK, 3) int32: x, y, pol
    const float* __restrict__ ts,      // (SN, SPK) f32, ascending
    const int*   __restrict__ tt,      // (SN, SPK) int32 in [0,8)
    const int*   __restrict__ length,  // (SN,) int32
    float*       __restrict__ out)     // (SN, 8, 2, 64, 64) f32
{
    __shared__ float    stsn[SPK];
    __shared__ unsigned hcnt[HB];      // 16 KB
    __shared__ unsigned lpk [SPK];     // ambiguous list: (t<<16)|key, time order
    __shared__ float    lCr [SPK];
    __shared__ int      snl [8];
    __shared__ float    sC  [8];
    __shared__ float    sU  [8];
    __shared__ int      wcnt[8];

    const int blk  = blockIdx.x;
    const int s    = blk >> 2;
    const int rblk = blk & 3;
    const int t    = threadIdx.x;      // event index n = t
    const int lane = t & 63;
    const int wid  = t >> 6;

    const int   len = length[s];
    const float ts0 = ts[s * SPK];

    // issue my event loads early
    const int* ev = event + (size_t)(s * SPK + t) * 3;
    const int   ex  = ev[0], ey = ev[1], ep = ev[2];
    const float tsn = ts[s * SPK + t];
    const int   tv  = tt[s * SPK + t];

    if (t < 8) snl[t] = -1;
#pragma unroll
    for (int k = 0; k < HB / SPK; ++k) hcnt[t + k * SPK] = 0u;
    __syncthreads();

    // ---- stage: snlast + hash counts ----
    const bool     gate = (t < len);                   // t==0 always (len>=1)
    const unsigned key  = (unsigned)((ep << 14) | (ex << 7) | ey);
    const float    d    = (ts0 - tsn) * 0.01f;         // TAU = 100
    const float    myCr = (PFRAC * (GMAX - GMIN)) * __expf(-d);   // 0.27/C(n)
    const unsigned h    = (key * 2654435761u) >> 20;   // 12-bit bucket
    stsn[t] = tsn;
    if (t >= 1) atomicMax(&snl[tv], t);
    if (gate)   atomicAdd(&hcnt[h], 1u);
    __syncthreads();

    // ---- ambiguity flag + wave counts; slot table on thread 0..7 ----
    const bool amb = gate && (hcnt[h] > 1u);
    const unsigned long long bmask = __ballot(amb);
    if (lane == 0) wcnt[wid] = (int)__popcll(bmask);
    if (t < 8) {
        int nr = snl[t];
        if (t == 0 && nr < 0) nr = 0;                  // slot0 -> init state
        float C = 0.0f, u = 0.0f;
        if (nr >= 0) {
            C = __expf((ts0 - stsn[nr]) * 0.01f);      // C_r <= 1
            u = GMIN - C * GMIN;                       // untouched value
        }
        snl[t] = nr;
        sC [t] = C;
        sU [t] = u;
    }
    __syncthreads();

    // ---- stable compaction of ambiguous events (time order) ----
    int base = 0, nA = 0;
#pragma unroll
    for (int w = 0; w < 8; ++w) {
        int c = wcnt[w];
        if (w < wid) base += c;
        nA += c;
    }
    if (amb) {
        int pos = base + (int)__popcll(bmask & ((1ull << lane) - 1ull));
        lpk[pos] = ((unsigned)t << 16) | key;
        lCr[pos] = myCr;
    }

    // ---- fill: 64 KB contiguous (2 slots x 2 pol x 64 x 64) ----
    {
        float4* o4 = reinterpret_cast<float4*>(out) + (size_t)(s * 8 + rblk * 2) * 2048;
        const float u0 = sU[rblk * 2];
        const float u1 = sU[rblk * 2 + 1];
#pragma unroll
        for (int k = 0; k < 8; ++k) {
            int f = k * 512 + t;                       // 0..4095 float4
            float u = (f < 2048) ? u0 : u1;
            o4[f] = make_float4(u, u, u, u);
        }
    }
    __syncthreads();   // lpk/lCr visible; fill stores drained before atomics

    // ---- own-prefix amplitude ----
    float a = -GMIN;
    if (gate) {
        if (amb) {
            for (int i = 0; i < nA; ++i) {
                unsigned e = lpk[i];
                if ((e & 0xFFFFu) == key && (e >> 16) < (unsigned)t)
                    a = ((e >> 16) == 0u)
                            ? (PFRAC * (GMAX - GMIN) - GMIN)       // init SETs 0.27
                            : fmaf(1.0f - PFRAC, a, lCr[i]);
            }
        }
        a = (t == 0) ? (PFRAC * (GMAX - GMIN) - GMIN)
                     : fmaf(1.0f - PFRAC, a, myCr);
    }

    // ---- scatter to this block's two slots ----
    if (gate) {
        const int Xo = ex >> 1, Yo = ey >> 1;
        int* oi = reinterpret_cast<int*>(out);
#pragma unroll
        for (int rl = 0; rl < 2; ++rl) {
            int r  = rblk * 2 + rl;
            int nr = snl[r];
            if (t <= nr) {
                float val = fmaf(sC[r], a, GMIN);      // >= u_r >= 0
                int   idx = (((s * 8 + r) * 2 + ep) * 64 + Xo) * 64 + Yo;
                atomicMax(oi + idx, __float_as_int(val));
            }
        }
    }
}

extern "C" void kernel_launch(void* const* d_in, const int* in_sizes, int n_in,
                              void* d_out, int out_size, void* d_ws, size_t ws_size,
                              hipStream_t stream) {
    const int*   event  = (const int*)  d_in[0];
    const float* ts     = (const float*)d_in[1];
    const int*   tt     = (const int*)  d_in[2];
    const int*   length = (const int*)  d_in[3];
    float*       out    = (float*)d_out;

    // 128 samples x 4 slot-pairs = 512 blocks x 512 threads
    fuse_kernel<<<dim3(SN * 4), dim3(512), 0, stream>>>(event, ts, tt, length, out);
}

// Round 18
// 16.852 us; speedup vs baseline: 2.3636x; 1.4869x over previous
//
#include <hip/hip_runtime.h>

#define SN 128
#define SPK 512

constexpr float GMIN  = 0.1f;
constexpr float PFRAC = 0.3f;
constexpr float GMAX  = 1.0f;

// LDS-composed output tile, single global writeout.
// Lazy decay: v(n) = C(n)*a + GMIN, C(n) = exp((ts0-ts[n])/TAU) <= 1.
// Untouched cell at snapshot r: u_r = GMIN*(1-C_r) (identical everywhere).
// Touch at n: a' = (1-PFRAC)*a + PFRAC*(GMAX-GMIN)/C(n); amplitude is
// non-decreasing over the touch prefix -> per-touch own-prefix candidates +
// max reproduce the exact final value (verified absmax 0.0, R11/R15/R17).
// Same-cell predecessors: hash-count buckets; only events in buckets with
// count>=2 are compacted (time order) and scanned (~60 iters, no false
// negatives since equal keys share a bucket).
//
// Block = (s, r): one output plane (2 pol x 64 x 64 = 32 KB) built in LDS:
// memset to u_r -> LDS atomicMax scatter -> coalesced 32 KB writeout.
// All atomics/barriers are LDS-local; global traffic = 10 MB reads + 33.5 MB
// streaming writes (irreducible).

__global__ __launch_bounds__(512, 4) void fuse_kernel(
    const int*   __restrict__ event,   // (SN, SPK, 3) int32: x, y, pol
    const float* __restrict__ ts,      // (SN, SPK) f32, ascending
    const int*   __restrict__ tt,      // (SN, SPK) int32 in [0,8)
    const int*   __restrict__ length,  // (SN,) int32
    float*       __restrict__ out)     // (SN, 8, 2, 64, 64) f32
{
    __shared__ int      tile[2 * 64 * 64];   // 32 KB; first 16 KB aliased as hcnt
    __shared__ unsigned lpk [SPK];           // ambiguous list: (t<<16)|key
    __shared__ float    lCr [SPK];
    __shared__ int      snl [8];
    __shared__ int      wcnt[8];
    __shared__ float    sCs;                 // C_r (valid iff nr >= 0)

    unsigned* hcnt = (unsigned*)tile;        // 4096 hash buckets (dead after amb)

    const int blk  = blockIdx.x;
    const int s    = blk >> 3;
    const int r    = blk & 7;
    const int t    = threadIdx.x;            // event index n = t
    const int lane = t & 63;
    const int wid  = t >> 6;

    const int   len = length[s];
    const float ts0 = ts[s * SPK];

    // issue my event loads early
    const int* ev = event + (size_t)(s * SPK + t) * 3;
    const int   ex  = ev[0], ey = ev[1], ep = ev[2];
    const float tsn = ts[s * SPK + t];
    const int   tv  = tt[s * SPK + t];

    if (t < 8) snl[t] = -1;
#pragma unroll
    for (int k = 0; k < 8; ++k) hcnt[t + k * 512] = 0u;
    __syncthreads();

    // ---- stage: snlast + hash counts (LDS atomics) ----
    const bool     gate = (t < len);                    // t==0 always (len>=1)
    const unsigned key  = (unsigned)((ep << 14) | (ex << 7) | ey);
    const float    d    = (ts0 - tsn) * 0.01f;          // TAU = 100
    const float    myCr = (PFRAC * (GMAX - GMIN)) * __expf(-d);   // 0.27/C(n)
    const unsigned h    = (key * 2654435761u) >> 20;    // 12-bit bucket
    if (t >= 1) atomicMax(&snl[tv], t);
    if (gate)   atomicAdd(&hcnt[h], 1u);
    __syncthreads();

    // ---- slot info + ambiguity flags (all hcnt reads happen here) ----
    int nr = snl[r];
    if (r == 0 && nr < 0) nr = 0;                       // slot0 -> init state
    const bool amb = gate && (hcnt[h] > 1u);
    if (t == nr) sCs = __expf((ts0 - tsn) * 0.01f);     // exactly one writer
    const unsigned long long bmask = __ballot(amb);
    if (lane == 0) wcnt[wid] = (int)__popcll(bmask);
    __syncthreads();                                    // hcnt dead from here

    // ---- compact ambiguous events (time order) + tile memset to u_r ----
    int base = 0, nA = 0;
#pragma unroll
    for (int w = 0; w < 8; ++w) {
        int c = wcnt[w];
        if (w < wid) base += c;
        nA += c;
    }
    if (amb) {
        int pos = base + (int)__popcll(bmask & ((1ull << lane) - 1ull));
        lpk[pos] = ((unsigned)t << 16) | key;
        lCr[pos] = myCr;
    }
    const float C_r = (nr >= 0) ? sCs : 0.0f;
    const int   ub  = __float_as_int((nr >= 0) ? (GMIN - C_r * GMIN) : 0.0f);
#pragma unroll
    for (int k = 0; k < 16; ++k) tile[t + k * 512] = ub;
    __syncthreads();                                    // tile + lpk/lCr ready

    // ---- own-prefix amplitude + LDS scatter ----
    if (gate && t <= nr) {
        float a = -GMIN;
        if (amb) {
            for (int i = 0; i < nA; ++i) {
                unsigned e = lpk[i];
                if ((e & 0xFFFFu) == key && (e >> 16) < (unsigned)t)
                    a = ((e >> 16) == 0u)
                            ? (PFRAC * (GMAX - GMIN) - GMIN)   // init SETs 0.27
                            : fmaf(1.0f - PFRAC, a, lCr[i]);
            }
        }
        a = (t == 0) ? (PFRAC * (GMAX - GMIN) - GMIN)
                     : fmaf(1.0f - PFRAC, a, myCr);
        float val = fmaf(C_r, a, GMIN);                 // >= u_r >= 0
        int   idx = (ep * 64 + (ex >> 1)) * 64 + (ey >> 1);
        atomicMax(&tile[idx], __float_as_int(val));
    }
    __syncthreads();

    // ---- single coalesced writeout: 2048 float4 ----
    float4*       o4 = reinterpret_cast<float4*>(out + (size_t)(s * 8 + r) * 8192);
    const float4* t4 = reinterpret_cast<const float4*>(tile);
#pragma unroll
    for (int k = 0; k < 4; ++k) o4[t + k * 512] = t4[t + k * 512];
}

extern "C" void kernel_launch(void* const* d_in, const int* in_sizes, int n_in,
                              void* d_out, int out_size, void* d_ws, size_t ws_size,
                              hipStream_t stream) {
    const int*   event  = (const int*)  d_in[0];
    const float* ts     = (const float*)d_in[1];
    const int*   tt     = (const int*)  d_in[2];
    const int*   length = (const int*)  d_in[3];
    float*       out    = (float*)d_out;

    // 128 samples x 8 slots = 1024 blocks x 512 threads
    fuse_kernel<<<dim3(SN * 8), dim3(512), 0, stream>>>(event, ts, tt, length, out);
}